// Round 5
// baseline (213.490 us; speedup 1.0000x reference)
//
#include <hip/hip_runtime.h>
#include <hip/hip_bf16.h>
#include <stdint.h>

// B=2, S=2048, D=1024, H=16, DH=64. Causal self-attention block, bf16 MFMA pipeline.

typedef __attribute__((ext_vector_type(8))) short bf16x8;   // 8 bf16 = 16B (A/B frag)
typedef __attribute__((ext_vector_type(4))) float f32x4;    // C/D frag 16x16
typedef __attribute__((ext_vector_type(16))) float f32x16;  // C/D frag 32x32
typedef __attribute__((ext_vector_type(4))) unsigned int u32x4;

typedef const __attribute__((address_space(1))) uint32_t* gp1_t;
typedef __attribute__((address_space(3))) uint32_t* lp3_t;

static __device__ __forceinline__ uint16_t f2b(float x) {
  __hip_bfloat16 h = __float2bfloat16(x);
  return *reinterpret_cast<uint16_t*>(&h);
}

// v_cvt_pk_bf16_f32: dst.lo = bf16(lo), dst.hi = bf16(hi)
static __device__ __forceinline__ uint32_t cvtpk(float lo, float hi) {
  uint32_t r;
  asm("v_cvt_pk_bf16_f32 %0, %1, %2" : "=v"(r) : "v"(lo), "v"(hi));
  return r;
}

// Stage R rows x 64 bf16 (128B = 8 chunks of 16B) tile into LDS (GEMMs only).
template <int ISSUES>
static __device__ __forceinline__ void stage64(const uint16_t* __restrict__ g, int gstride,
                                               uint8_t* lds, int t) {
#pragma unroll
  for (int i = 0; i < ISSUES; ++i) {
    int p = i * 256 + t;          // 16B-chunk index
    int row = p >> 3, c = p & 7;
    const uint16_t* src = g + row * gstride + ((c ^ (row & 7)) << 3);
    __builtin_amdgcn_global_load_lds((gp1_t)src, (lp3_t)(lds + (p & ~63) * 16), 16, 0, 0);
  }
}

// Read a 16B fragment from a swizzled [R][64] bf16 tile: 8 bf16 at (row, chunk*8).
static __device__ __forceinline__ bf16x8 ld_frag(const uint8_t* lds, int row, int chunk) {
  return *(const bf16x8*)(lds + row * 128 + (((chunk) ^ (row & 7)) << 4));
}

// ---------------- f32 -> bf16 convert ----------------
__global__ __launch_bounds__(256) void cvtk(const float* __restrict__ in,
                                            uint16_t* __restrict__ out, int n4) {
  int i = blockIdx.x * 256 + threadIdx.x;
  if (i >= n4) return;
  float4 v = ((const float4*)in)[i];
  ushort4 o;
  o.x = f2b(v.x); o.y = f2b(v.y); o.z = f2b(v.z); o.w = f2b(v.w);
  ((ushort4*)out)[i] = o;
}

// ---------------- GEMM1: qkv = x @ w_in^T + b_in ----------------
// Epilogue: Q pre-scaled by 1/sqrt(DH)*log2(e) (softmax done in exp2 domain).
// V stored transposed (B,H,DH,S) with column bits 2<->3 swapped inside each
// 16-col block, so attention's PV B-fragments are contiguous 16B loads while
// P stays fully lane-local (kv(ks,hi,j) = 32(ks>>1)+16(ks&1)+8(j>>2)+4hi+(j&3)).
__global__ __launch_bounds__(256) void gemm_qkv(const uint16_t* __restrict__ A,
                                                const uint16_t* __restrict__ W,
                                                const float* __restrict__ bias,
                                                uint16_t* __restrict__ Qb,
                                                uint16_t* __restrict__ Kb,
                                                uint16_t* __restrict__ Vt) {
  __shared__ uint8_t sm[32768];
  uint8_t* As = sm;
  uint8_t* Bs = sm + 16384;
  int t = threadIdx.x, l = t & 63, w = t >> 6;
  int m0 = blockIdx.y * 128, n0 = blockIdx.x * 128;
  int wr = (w >> 1) * 64, wc = (w & 1) * 64;
  const f32x4 fz = {0.f, 0.f, 0.f, 0.f};
  f32x4 acc[4][4];
#pragma unroll
  for (int i = 0; i < 4; ++i)
#pragma unroll
    for (int j = 0; j < 4; ++j) acc[i][j] = fz;

  for (int kt = 0; kt < 16; ++kt) {
    __syncthreads();
    stage64<4>(A + m0 * 1024 + kt * 64, 1024, As, t);
    stage64<4>(W + n0 * 1024 + kt * 64, 1024, Bs, t);
    __syncthreads();
#pragma unroll
    for (int ks = 0; ks < 2; ++ks) {
      bf16x8 a[4], b[4];
#pragma unroll
      for (int i = 0; i < 4; ++i) {
        a[i] = ld_frag(As, wr + i * 16 + (l & 15), ks * 4 + (l >> 4));
        b[i] = ld_frag(Bs, wc + i * 16 + (l & 15), ks * 4 + (l >> 4));
      }
#pragma unroll
      for (int i = 0; i < 4; ++i)
#pragma unroll
        for (int j = 0; j < 4; ++j)
          acc[i][j] = __builtin_amdgcn_mfma_f32_16x16x32_bf16(a[i], b[j], acc[i][j], 0, 0, 0);
    }
  }
  const float CSQ = 0.18033688011112042f;  // 0.125 * log2(e)
#pragma unroll
  for (int j = 0; j < 4; ++j) {
    int e = n0 + wc + j * 16 + (l & 15);
    float bv = bias[e];
    int sec = e >> 10, ec = e & 1023, h = ec >> 6, dh = ec & 63;
#pragma unroll
    for (int i = 0; i < 4; ++i) {
      int mb = m0 + wr + i * 16 + ((l >> 4) << 2);
#pragma unroll
      for (int r = 0; r < 4; ++r) {
        int m = mb + r, bb = m >> 11, s = m & 2047;
        float v = acc[i][j][r] + bv;
        if (sec == 0) {
          Qb[(((bb * 16 + h) * 2048 + s) << 6) + dh] = f2b(v * CSQ);
        } else if (sec == 1) {
          Kb[(((bb * 16 + h) * 2048 + s) << 6) + dh] = f2b(v);
        } else {
          int sp = (s & ~12) | ((s & 4) << 1) | ((s & 8) >> 1);  // swap col bits 2,3
          Vt[(((bb * 16 + h) << 6) + dh) * 2048 + sp] = f2b(v);
        }
      }
    }
  }
}

// ---------------- GEMM2: out = att @ w_out^T + b_out (f32 out) ----------------
__global__ __launch_bounds__(256) void gemm_out(const uint16_t* __restrict__ A,
                                                const uint16_t* __restrict__ W,
                                                const float* __restrict__ bias,
                                                float* __restrict__ out) {
  __shared__ uint8_t sm[32768];
  uint8_t* As = sm;
  uint8_t* Bs = sm + 16384;
  int t = threadIdx.x, l = t & 63, w = t >> 6;
  int m0 = blockIdx.y * 128, n0 = blockIdx.x * 128;
  int wr = (w >> 1) * 64, wc = (w & 1) * 64;
  const f32x4 fz = {0.f, 0.f, 0.f, 0.f};
  f32x4 acc[4][4];
#pragma unroll
  for (int i = 0; i < 4; ++i)
#pragma unroll
    for (int j = 0; j < 4; ++j) acc[i][j] = fz;

  for (int kt = 0; kt < 16; ++kt) {
    __syncthreads();
    stage64<4>(A + m0 * 1024 + kt * 64, 1024, As, t);
    stage64<4>(W + n0 * 1024 + kt * 64, 1024, Bs, t);
    __syncthreads();
#pragma unroll
    for (int ks = 0; ks < 2; ++ks) {
      bf16x8 a[4], b[4];
#pragma unroll
      for (int i = 0; i < 4; ++i) {
        a[i] = ld_frag(As, wr + i * 16 + (l & 15), ks * 4 + (l >> 4));
        b[i] = ld_frag(Bs, wc + i * 16 + (l & 15), ks * 4 + (l >> 4));
      }
#pragma unroll
      for (int i = 0; i < 4; ++i)
#pragma unroll
        for (int j = 0; j < 4; ++j)
          acc[i][j] = __builtin_amdgcn_mfma_f32_16x16x32_bf16(a[i], b[j], acc[i][j], 0, 0, 0);
    }
  }
#pragma unroll
  for (int j = 0; j < 4; ++j) {
    int e = n0 + wc + j * 16 + (l & 15);
    float bv = bias[e];
#pragma unroll
    for (int i = 0; i < 4; ++i) {
      int mb = m0 + wr + i * 16 + ((l >> 4) << 2);
#pragma unroll
      for (int r = 0; r < 4; ++r) {
        int m = mb + r;
        out[m * 1024 + e] = acc[i][j][r] + bv;
      }
    }
  }
}

// ---------------- Flash attention (causal): 1 wave/block, registers-only ----------------
// Software-pipelined: two named K/V register sets (A/B); while computing tile t
// from one set, the other set's 16 global loads for tile t+1 are in flight.
static __device__ __forceinline__ void load_kv(const uint16_t* __restrict__ kp,
                                               const uint16_t* __restrict__ vp,
                                               bf16x8 kf[2][4], bf16x8 vf[2][4]) {
#pragma unroll
  for (int f = 0; f < 2; ++f)
#pragma unroll
    for (int ks = 0; ks < 4; ++ks)
      kf[f][ks] = *(const bf16x8*)(kp + (f << 11) + ks * 16);
#pragma unroll
  for (int n = 0; n < 2; ++n)
#pragma unroll
    for (int ks = 0; ks < 4; ++ks)
      vf[n][ks] = *(const bf16x8*)(vp + n * 65536 + ks * 16);
}

static __device__ __forceinline__ void attn_tile(const bf16x8 kf[2][4], const bf16x8 vf[2][4],
                                                 const bf16x8 qf[4], f32x16 acco[2],
                                                 float& mrun, float& lsum,
                                                 int tt, int q0, int q, int hi, bool causal) {
  // QK^T: sc[f][r] = S[kv = tt*64 + f*32 + crow(r,hi)][q]  (already exp2-scaled)
  f32x16 sc[2];
#pragma unroll
  for (int r = 0; r < 16; ++r) { sc[0][r] = 0.f; sc[1][r] = 0.f; }
  __builtin_amdgcn_s_setprio(1);
#pragma unroll
  for (int f = 0; f < 2; ++f)
#pragma unroll
    for (int ks = 0; ks < 4; ++ks)
      sc[f] = __builtin_amdgcn_mfma_f32_32x32x16_bf16(kf[f][ks], qf[ks], sc[f], 0, 0, 0);
  __builtin_amdgcn_s_setprio(0);

  // causal mask + running max (in place on sc)
  float tm = -1e30f;
  bool nomask = (!causal) || (tt * 64 + 63 <= q0);
#pragma unroll
  for (int f = 0; f < 2; ++f)
#pragma unroll
    for (int r = 0; r < 16; ++r) {
      float v = sc[f][r];
      if (!nomask) {
        int kv = tt * 64 + f * 32 + ((r & 3) + 8 * (r >> 2) + 4 * hi);
        v = (kv <= q) ? v : -1e30f;
      }
      sc[f][r] = v;
      tm = fmaxf(tm, v);
    }
  tm = fmaxf(tm, __shfl_xor(tm, 32));

  // defer-max (T13): skip rescale when max growth small
  bool defer = __all(tm <= mrun + 8.0f);
  if (!defer) {
    float mnew = fmaxf(mrun, tm);
    float alpha = exp2f(mrun - mnew);
    mrun = mnew;
    lsum *= alpha;
#pragma unroll
    for (int r = 0; r < 16; ++r) {
      float av = __shfl(alpha, (r & 3) + 8 * (r >> 2) + 4 * hi);
      acco[0][r] *= av;
      acco[1][r] *= av;
    }
  }
  float rs = 0.f;
#pragma unroll
  for (int f = 0; f < 2; ++f)
#pragma unroll
    for (int r = 0; r < 16; ++r) {
      float e = exp2f(sc[f][r] - mrun);
      sc[f][r] = e;
      rs += e;
    }
  rs += __shfl_xor(rs, 32);
  lsum += rs;

  // PV with lane-local P fragments (zero cross-lane):
  __builtin_amdgcn_s_setprio(1);
#pragma unroll
  for (int ks = 0; ks < 4; ++ks) {
    int f = ks >> 1, a8 = (ks & 1) * 8;
    u32x4 wv = {cvtpk(sc[f][a8 + 0], sc[f][a8 + 1]),
                cvtpk(sc[f][a8 + 2], sc[f][a8 + 3]),
                cvtpk(sc[f][a8 + 4], sc[f][a8 + 5]),
                cvtpk(sc[f][a8 + 6], sc[f][a8 + 7])};
    bf16x8 af = __builtin_bit_cast(bf16x8, wv);
#pragma unroll
    for (int n = 0; n < 2; ++n)
      acco[n] = __builtin_amdgcn_mfma_f32_32x32x16_bf16(af, vf[n][ks], acco[n], 0, 0, 0);
  }
  __builtin_amdgcn_s_setprio(0);
}

__global__ __launch_bounds__(64) void attn(const uint16_t* __restrict__ Qb,
                                           const uint16_t* __restrict__ Kb,
                                           const uint16_t* __restrict__ Vt,
                                           uint16_t* __restrict__ Ab,
                                           const int* __restrict__ maskp) {
  int l = threadIdx.x & 63;
  int hi = l >> 5, ql = l & 31;
  int qt = 63 - (int)blockIdx.x;    // heavy blocks dispatched first
  int bh = blockIdx.y;
  bool causal = (*maskp != 0);
  int nt = causal ? ((qt >> 1) + 1) : 32;
  int q0 = qt * 32;
  int q = q0 + ql;

  // Q fragments (B-operand): Q[q][dh = ks*16 + hi*8 + j], pre-scaled by CSQ
  bf16x8 qf[4];
  const uint16_t* Qp = Qb + (((size_t)bh * 2048 + q) << 6) + hi * 8;
#pragma unroll
  for (int ks = 0; ks < 4; ++ks) qf[ks] = *(const bf16x8*)(Qp + ks * 16);

  const uint16_t* Kp = Kb + (((size_t)bh * 2048) << 6) + (ql << 6) + hi * 8;
  const uint16_t* Vp = Vt + (size_t)bh * 131072 + (size_t)ql * 2048 + hi * 8;

  f32x16 acco[2];
#pragma unroll
  for (int r = 0; r < 16; ++r) { acco[0][r] = 0.f; acco[1][r] = 0.f; }
  float mrun = -1e30f, lsum = 0.f;

  bf16x8 kfA[2][4], vfA[2][4], kfB[2][4], vfB[2][4];
  load_kv(Kp, Vp, kfA, vfA);

  int tt = 0;
  for (; tt + 1 < nt; tt += 2) {
    load_kv(Kp + ((tt + 1) << 12), Vp + (tt + 1) * 64, kfB, vfB);   // prefetch t+1
    attn_tile(kfA, vfA, qf, acco, mrun, lsum, tt, q0, q, hi, causal);
    if (tt + 2 < nt)
      load_kv(Kp + ((tt + 2) << 12), Vp + (tt + 2) * 64, kfA, vfA); // prefetch t+2
    attn_tile(kfB, vfB, qf, acco, mrun, lsum, tt + 1, q0, q, hi, causal);
  }
  if (tt < nt)
    attn_tile(kfA, vfA, qf, acco, mrun, lsum, tt, q0, q, hi, causal);

  // epilogue: O[q = q0 + crow(r,hi)][dh = n*32 + ql] / lsum[q]
  int bb = bh >> 4, h = bh & 15;
#pragma unroll
  for (int r = 0; r < 16; ++r) {
    int crow = (r & 3) + 8 * (r >> 2) + 4 * hi;
    float ls = __shfl(lsum, crow);
    float inv = 1.0f / ls;
    int qg = q0 + crow;
#pragma unroll
    for (int n = 0; n < 2; ++n)
      Ab[(((size_t)(bb * 2048 + qg)) << 10) + h * 64 + n * 32 + ql] = f2b(acco[n][r] * inv);
  }
}

extern "C" void kernel_launch(void* const* d_in, const int* in_sizes, int n_in,
                              void* d_out, int out_size, void* d_ws, size_t ws_size,
                              hipStream_t stream) {
  const float* x     = (const float*)d_in[0];
  const float* w_in  = (const float*)d_in[1];
  const float* b_in  = (const float*)d_in[2];
  const float* w_out = (const float*)d_in[3];
  const float* b_out = (const float*)d_in[4];
  const int*   mask  = (const int*)d_in[5];
  float* out = (float*)d_out;

  uint8_t* ws = (uint8_t*)d_ws;
  uint16_t* xb  = (uint16_t*)(ws);                  // 8 MB  x bf16 [4096][1024]
  uint16_t* wib = (uint16_t*)(ws + (8u << 20));     // 6 MB  w_in bf16 [3072][1024]
  uint16_t* wob = (uint16_t*)(ws + (14u << 20));    // 2 MB  w_out bf16 [1024][1024]
  uint16_t* Qb  = (uint16_t*)(ws + (16u << 20));    // 8 MB  (B,H,S,DH) pre-scaled
  uint16_t* Kb  = (uint16_t*)(ws + (24u << 20));    // 8 MB  (B,H,S,DH)
  uint16_t* Vt  = (uint16_t*)(ws + (32u << 20));    // 8 MB  (B,H,DH,S) col-permuted
  uint16_t* Ab  = (uint16_t*)(ws + (40u << 20));    // 8 MB  att (B,S,D) bf16

  cvtk<<<4096, 256, 0, stream>>>(x, xb, 4096 * 1024 / 4);
  cvtk<<<3072, 256, 0, stream>>>(w_in, wib, 3072 * 1024 / 4);
  cvtk<<<1024, 256, 0, stream>>>(w_out, wob, 1024 * 1024 / 4);
  gemm_qkv<<<dim3(24, 32), 256, 0, stream>>>(xb, wib, b_in, Qb, Kb, Vt);
  attn<<<dim3(64, 32), 64, 0, stream>>>(Qb, Kb, Vt, Ab, mask);
  gemm_out<<<dim3(8, 32), 256, 0, stream>>>(Ab, wob, b_out, out);
}

// Round 6
// 201.167 us; speedup vs baseline: 1.0613x; 1.0613x over previous
//
#include <hip/hip_runtime.h>
#include <hip/hip_bf16.h>
#include <stdint.h>

// B=2, S=2048, D=1024, H=16, DH=64. Causal self-attention block, bf16 MFMA pipeline.

typedef __attribute__((ext_vector_type(8))) short bf16x8;   // 8 bf16 = 16B (A/B frag)
typedef __attribute__((ext_vector_type(4))) float f32x4;    // C/D frag 16x16
typedef __attribute__((ext_vector_type(16))) float f32x16;  // C/D frag 32x32
typedef __attribute__((ext_vector_type(4))) unsigned int u32x4;

typedef const __attribute__((address_space(1))) uint32_t* gp1_t;
typedef __attribute__((address_space(3))) uint32_t* lp3_t;

static __device__ __forceinline__ uint16_t f2b(float x) {
  __hip_bfloat16 h = __float2bfloat16(x);
  return *reinterpret_cast<uint16_t*>(&h);
}

// v_cvt_pk_bf16_f32: dst.lo = bf16(lo), dst.hi = bf16(hi)
static __device__ __forceinline__ uint32_t cvtpk(float lo, float hi) {
  uint32_t r;
  asm("v_cvt_pk_bf16_f32 %0, %1, %2" : "=v"(r) : "v"(lo), "v"(hi));
  return r;
}

// Stage R rows x 64 bf16 (128B = 8 chunks of 16B) tile into LDS (GEMMs only).
template <int ISSUES>
static __device__ __forceinline__ void stage64(const uint16_t* __restrict__ g, int gstride,
                                               uint8_t* lds, int t) {
#pragma unroll
  for (int i = 0; i < ISSUES; ++i) {
    int p = i * 256 + t;          // 16B-chunk index
    int row = p >> 3, c = p & 7;
    const uint16_t* src = g + row * gstride + ((c ^ (row & 7)) << 3);
    __builtin_amdgcn_global_load_lds((gp1_t)src, (lp3_t)(lds + (p & ~63) * 16), 16, 0, 0);
  }
}

// Read a 16B fragment from a swizzled [R][64] bf16 tile: 8 bf16 at (row, chunk*8).
static __device__ __forceinline__ bf16x8 ld_frag(const uint8_t* lds, int row, int chunk) {
  return *(const bf16x8*)(lds + row * 128 + (((chunk) ^ (row & 7)) << 4));
}

// ---------------- f32 -> bf16 convert ----------------
__global__ __launch_bounds__(256) void cvtk(const float* __restrict__ in,
                                            uint16_t* __restrict__ out, int n4) {
  int i = blockIdx.x * 256 + threadIdx.x;
  if (i >= n4) return;
  float4 v = ((const float4*)in)[i];
  ushort4 o;
  o.x = f2b(v.x); o.y = f2b(v.y); o.z = f2b(v.z); o.w = f2b(v.w);
  ((ushort4*)out)[i] = o;
}

// ---------------- GEMM1: qkv = x @ w_in^T + b_in ----------------
// Epilogue: Q pre-scaled by 1/sqrt(DH)*log2(e) (softmax done in exp2 domain).
// V stored transposed (B,H,DH,S) with column bits 2<->3 swapped inside each
// 16-col block, so attention's PV B-fragments are contiguous 16B loads while
// P stays fully lane-local (kv(ks,hi,j) = 32(ks>>1)+16(ks&1)+8(j>>2)+4hi+(j&3)).
__global__ __launch_bounds__(256) void gemm_qkv(const uint16_t* __restrict__ A,
                                                const uint16_t* __restrict__ W,
                                                const float* __restrict__ bias,
                                                uint16_t* __restrict__ Qb,
                                                uint16_t* __restrict__ Kb,
                                                uint16_t* __restrict__ Vt) {
  __shared__ uint8_t sm[32768];
  uint8_t* As = sm;
  uint8_t* Bs = sm + 16384;
  int t = threadIdx.x, l = t & 63, w = t >> 6;
  int m0 = blockIdx.y * 128, n0 = blockIdx.x * 128;
  int wr = (w >> 1) * 64, wc = (w & 1) * 64;
  const f32x4 fz = {0.f, 0.f, 0.f, 0.f};
  f32x4 acc[4][4];
#pragma unroll
  for (int i = 0; i < 4; ++i)
#pragma unroll
    for (int j = 0; j < 4; ++j) acc[i][j] = fz;

  for (int kt = 0; kt < 16; ++kt) {
    __syncthreads();
    stage64<4>(A + m0 * 1024 + kt * 64, 1024, As, t);
    stage64<4>(W + n0 * 1024 + kt * 64, 1024, Bs, t);
    __syncthreads();
#pragma unroll
    for (int ks = 0; ks < 2; ++ks) {
      bf16x8 a[4], b[4];
#pragma unroll
      for (int i = 0; i < 4; ++i) {
        a[i] = ld_frag(As, wr + i * 16 + (l & 15), ks * 4 + (l >> 4));
        b[i] = ld_frag(Bs, wc + i * 16 + (l & 15), ks * 4 + (l >> 4));
      }
#pragma unroll
      for (int i = 0; i < 4; ++i)
#pragma unroll
        for (int j = 0; j < 4; ++j)
          acc[i][j] = __builtin_amdgcn_mfma_f32_16x16x32_bf16(a[i], b[j], acc[i][j], 0, 0, 0);
    }
  }
  const float CSQ = 0.18033688011112042f;  // 0.125 * log2(e)
#pragma unroll
  for (int j = 0; j < 4; ++j) {
    int e = n0 + wc + j * 16 + (l & 15);
    float bv = bias[e];
    int sec = e >> 10, ec = e & 1023, h = ec >> 6, dh = ec & 63;
#pragma unroll
    for (int i = 0; i < 4; ++i) {
      int mb = m0 + wr + i * 16 + ((l >> 4) << 2);
#pragma unroll
      for (int r = 0; r < 4; ++r) {
        int m = mb + r, bb = m >> 11, s = m & 2047;
        float v = acc[i][j][r] + bv;
        if (sec == 0) {
          Qb[(((bb * 16 + h) * 2048 + s) << 6) + dh] = f2b(v * CSQ);
        } else if (sec == 1) {
          Kb[(((bb * 16 + h) * 2048 + s) << 6) + dh] = f2b(v);
        } else {
          int sp = (s & ~12) | ((s & 4) << 1) | ((s & 8) >> 1);  // swap col bits 2,3
          Vt[(((bb * 16 + h) << 6) + dh) * 2048 + sp] = f2b(v);
        }
      }
    }
  }
}

// ---------------- GEMM2: out = att @ w_out^T + b_out (f32 out) ----------------
__global__ __launch_bounds__(256) void gemm_out(const uint16_t* __restrict__ A,
                                                const uint16_t* __restrict__ W,
                                                const float* __restrict__ bias,
                                                float* __restrict__ out) {
  __shared__ uint8_t sm[32768];
  uint8_t* As = sm;
  uint8_t* Bs = sm + 16384;
  int t = threadIdx.x, l = t & 63, w = t >> 6;
  int m0 = blockIdx.y * 128, n0 = blockIdx.x * 128;
  int wr = (w >> 1) * 64, wc = (w & 1) * 64;
  const f32x4 fz = {0.f, 0.f, 0.f, 0.f};
  f32x4 acc[4][4];
#pragma unroll
  for (int i = 0; i < 4; ++i)
#pragma unroll
    for (int j = 0; j < 4; ++j) acc[i][j] = fz;

  for (int kt = 0; kt < 16; ++kt) {
    __syncthreads();
    stage64<4>(A + m0 * 1024 + kt * 64, 1024, As, t);
    stage64<4>(W + n0 * 1024 + kt * 64, 1024, Bs, t);
    __syncthreads();
#pragma unroll
    for (int ks = 0; ks < 2; ++ks) {
      bf16x8 a[4], b[4];
#pragma unroll
      for (int i = 0; i < 4; ++i) {
        a[i] = ld_frag(As, wr + i * 16 + (l & 15), ks * 4 + (l >> 4));
        b[i] = ld_frag(Bs, wc + i * 16 + (l & 15), ks * 4 + (l >> 4));
      }
#pragma unroll
      for (int i = 0; i < 4; ++i)
#pragma unroll
        for (int j = 0; j < 4; ++j)
          acc[i][j] = __builtin_amdgcn_mfma_f32_16x16x32_bf16(a[i], b[j], acc[i][j], 0, 0, 0);
    }
  }
#pragma unroll
  for (int j = 0; j < 4; ++j) {
    int e = n0 + wc + j * 16 + (l & 15);
    float bv = bias[e];
#pragma unroll
    for (int i = 0; i < 4; ++i) {
      int mb = m0 + wr + i * 16 + ((l >> 4) << 2);
#pragma unroll
      for (int r = 0; r < 4; ++r) {
        int m = mb + r;
        out[m * 1024 + e] = acc[i][j][r] + bv;
      }
    }
  }
}

// ---------------- Flash attention (causal): kv-split across 4 waves ----------------
// Grid (64 qt [reversed], 32 bh), 256 threads = 4 waves. All waves share the same
// 32 q-rows; wave w handles kv tiles tt = w, w+4, ... with private (m, l, acco).
// Register-direct K/V (V pre-permuted by gemm_qkv). End merge via padded LDS.
static __device__ __forceinline__ void load_kv(const uint16_t* __restrict__ kp,
                                               const uint16_t* __restrict__ vp,
                                               bf16x8 kf[2][4], bf16x8 vf[2][4]) {
#pragma unroll
  for (int f = 0; f < 2; ++f)
#pragma unroll
    for (int ks = 0; ks < 4; ++ks)
      kf[f][ks] = *(const bf16x8*)(kp + (f << 11) + ks * 16);
#pragma unroll
  for (int n = 0; n < 2; ++n)
#pragma unroll
    for (int ks = 0; ks < 4; ++ks)
      vf[n][ks] = *(const bf16x8*)(vp + n * 65536 + ks * 16);
}

static __device__ __forceinline__ void attn_tile(const bf16x8 kf[2][4], const bf16x8 vf[2][4],
                                                 const bf16x8 qf[4], f32x16 acco[2],
                                                 float& mrun, float& lsum,
                                                 int tt, int q0, int q, int hi, bool causal) {
  // QK^T: sc[f][r] = S[kv = tt*64 + f*32 + crow(r,hi)][q]  (already exp2-scaled)
  f32x16 sc[2];
#pragma unroll
  for (int r = 0; r < 16; ++r) { sc[0][r] = 0.f; sc[1][r] = 0.f; }
  __builtin_amdgcn_s_setprio(1);
#pragma unroll
  for (int f = 0; f < 2; ++f)
#pragma unroll
    for (int ks = 0; ks < 4; ++ks)
      sc[f] = __builtin_amdgcn_mfma_f32_32x32x16_bf16(kf[f][ks], qf[ks], sc[f], 0, 0, 0);
  __builtin_amdgcn_s_setprio(0);

  // causal mask + running max (in place on sc)
  float tm = -1e30f;
  bool nomask = (!causal) || (tt * 64 + 63 <= q0);
#pragma unroll
  for (int f = 0; f < 2; ++f)
#pragma unroll
    for (int r = 0; r < 16; ++r) {
      float v = sc[f][r];
      if (!nomask) {
        int kv = tt * 64 + f * 32 + ((r & 3) + 8 * (r >> 2) + 4 * hi);
        v = (kv <= q) ? v : -1e30f;
      }
      sc[f][r] = v;
      tm = fmaxf(tm, v);
    }
  tm = fmaxf(tm, __shfl_xor(tm, 32));

  // defer-max (T13): skip rescale when max growth small
  bool defer = __all(tm <= mrun + 8.0f);
  if (!defer) {
    float mnew = fmaxf(mrun, tm);
    float alpha = exp2f(mrun - mnew);
    mrun = mnew;
    lsum *= alpha;
#pragma unroll
    for (int r = 0; r < 16; ++r) {
      float av = __shfl(alpha, (r & 3) + 8 * (r >> 2) + 4 * hi);
      acco[0][r] *= av;
      acco[1][r] *= av;
    }
  }
  float rs = 0.f;
#pragma unroll
  for (int f = 0; f < 2; ++f)
#pragma unroll
    for (int r = 0; r < 16; ++r) {
      float e = exp2f(sc[f][r] - mrun);
      sc[f][r] = e;
      rs += e;
    }
  rs += __shfl_xor(rs, 32);
  lsum += rs;

  // PV with lane-local P fragments (zero cross-lane):
  __builtin_amdgcn_s_setprio(1);
#pragma unroll
  for (int ks = 0; ks < 4; ++ks) {
    int f = ks >> 1, a8 = (ks & 1) * 8;
    u32x4 wv = {cvtpk(sc[f][a8 + 0], sc[f][a8 + 1]),
                cvtpk(sc[f][a8 + 2], sc[f][a8 + 3]),
                cvtpk(sc[f][a8 + 4], sc[f][a8 + 5]),
                cvtpk(sc[f][a8 + 6], sc[f][a8 + 7])};
    bf16x8 af = __builtin_bit_cast(bf16x8, wv);
#pragma unroll
    for (int n = 0; n < 2; ++n)
      acco[n] = __builtin_amdgcn_mfma_f32_32x32x16_bf16(af, vf[n][ks], acco[n], 0, 0, 0);
  }
  __builtin_amdgcn_s_setprio(0);
}

__global__ __launch_bounds__(256) void attn(const uint16_t* __restrict__ Qb,
                                            const uint16_t* __restrict__ Kb,
                                            const uint16_t* __restrict__ Vt,
                                            uint16_t* __restrict__ Ab,
                                            const int* __restrict__ maskp) {
  __shared__ float oaccS[4][64][33];  // [wave][lane][reg], +1 pad -> conflict-free
  __shared__ float mlS[4][32][2];     // [wave][qrow][m,l]
  int t = threadIdx.x, l = t & 63, w = t >> 6;
  int hi = l >> 5, ql = l & 31;
  int qt = 63 - (int)blockIdx.x;    // heavy blocks dispatched first
  int bh = blockIdx.y;
  bool causal = (*maskp != 0);
  int nt = causal ? ((qt >> 1) + 1) : 32;
  int q0 = qt * 32;
  int q = q0 + ql;

  // Q fragments (B-operand): Q[q][dh = ks*16 + hi*8 + j], pre-scaled by CSQ
  bf16x8 qf[4];
  const uint16_t* Qp = Qb + (((size_t)bh * 2048 + q) << 6) + hi * 8;
#pragma unroll
  for (int ks = 0; ks < 4; ++ks) qf[ks] = *(const bf16x8*)(Qp + ks * 16);

  const uint16_t* Kp = Kb + (((size_t)bh * 2048) << 6) + (ql << 6) + hi * 8;
  const uint16_t* Vp = Vt + (size_t)bh * 131072 + (size_t)ql * 2048 + hi * 8;

  f32x16 acco[2];
#pragma unroll
  for (int r = 0; r < 16; ++r) { acco[0][r] = 0.f; acco[1][r] = 0.f; }
  float mrun = -1e30f, lsum = 0.f;

  // wave w handles tiles w, w+4, w+8, ...
  for (int tt = w; tt < nt; tt += 4) {
    bf16x8 kf[2][4], vf[2][4];
    load_kv(Kp + ((size_t)tt << 12), Vp + tt * 64, kf, vf);
    attn_tile(kf, vf, qf, acco, mrun, lsum, tt, q0, q, hi, causal);
  }

  // ---- merge the 4 kv-split partials ----
  if (hi == 0) { mlS[w][ql][0] = mrun; mlS[w][ql][1] = lsum; }
#pragma unroll
  for (int r = 0; r < 16; ++r) {
    oaccS[w][l][r] = acco[0][r];
    oaccS[w][l][16 + r] = acco[1][r];
  }
  __syncthreads();

  // wave w merges register subset r in [4w, 4w+4)  (rows 8w + 4hi + 0..3)
  int bb = bh >> 4, h = bh & 15;
#pragma unroll
  for (int rr = 0; rr < 4; ++rr) {
    int row = 8 * w + 4 * hi + rr;
    int r = 4 * w + rr;
    float m0v = mlS[0][row][0], m1v = mlS[1][row][0];
    float m2v = mlS[2][row][0], m3v = mlS[3][row][0];
    float M = fmaxf(fmaxf(m0v, m1v), fmaxf(m2v, m3v));
    float w0 = exp2f(m0v - M), w1 = exp2f(m1v - M);
    float w2 = exp2f(m2v - M), w3 = exp2f(m3v - M);
    float L = w0 * mlS[0][row][1] + w1 * mlS[1][row][1] +
              w2 * mlS[2][row][1] + w3 * mlS[3][row][1];
    float inv = 1.0f / L;
    int qg = q0 + row;
#pragma unroll
    for (int n = 0; n < 2; ++n) {
      float s = w0 * oaccS[0][l][n * 16 + r] + w1 * oaccS[1][l][n * 16 + r] +
                w2 * oaccS[2][l][n * 16 + r] + w3 * oaccS[3][l][n * 16 + r];
      Ab[(((size_t)(bb * 2048 + qg)) << 10) + h * 64 + n * 32 + ql] = f2b(s * inv);
    }
  }
}

extern "C" void kernel_launch(void* const* d_in, const int* in_sizes, int n_in,
                              void* d_out, int out_size, void* d_ws, size_t ws_size,
                              hipStream_t stream) {
  const float* x     = (const float*)d_in[0];
  const float* w_in  = (const float*)d_in[1];
  const float* b_in  = (const float*)d_in[2];
  const float* w_out = (const float*)d_in[3];
  const float* b_out = (const float*)d_in[4];
  const int*   mask  = (const int*)d_in[5];
  float* out = (float*)d_out;

  uint8_t* ws = (uint8_t*)d_ws;
  uint16_t* xb  = (uint16_t*)(ws);                  // 8 MB  x bf16 [4096][1024]
  uint16_t* wib = (uint16_t*)(ws + (8u << 20));     // 6 MB  w_in bf16 [3072][1024]
  uint16_t* wob = (uint16_t*)(ws + (14u << 20));    // 2 MB  w_out bf16 [1024][1024]
  uint16_t* Qb  = (uint16_t*)(ws + (16u << 20));    // 8 MB  (B,H,S,DH) pre-scaled
  uint16_t* Kb  = (uint16_t*)(ws + (24u << 20));    // 8 MB  (B,H,S,DH)
  uint16_t* Vt  = (uint16_t*)(ws + (32u << 20));    // 8 MB  (B,H,DH,S) col-permuted
  uint16_t* Ab  = (uint16_t*)(ws + (40u << 20));    // 8 MB  att (B,S,D) bf16

  cvtk<<<4096, 256, 0, stream>>>(x, xb, 4096 * 1024 / 4);
  cvtk<<<3072, 256, 0, stream>>>(w_in, wib, 3072 * 1024 / 4);
  cvtk<<<1024, 256, 0, stream>>>(w_out, wob, 1024 * 1024 / 4);
  gemm_qkv<<<dim3(24, 32), 256, 0, stream>>>(xb, wib, b_in, Qb, Kb, Vt);
  attn<<<dim3(64, 32), 256, 0, stream>>>(Qb, Kb, Vt, Ab, mask);
  gemm_out<<<dim3(8, 32), 256, 0, stream>>>(Ab, wob, b_out, out);
}

// Round 7
// 174.123 us; speedup vs baseline: 1.2261x; 1.1553x over previous
//
#include <hip/hip_runtime.h>
#include <hip/hip_bf16.h>
#include <stdint.h>

// B=2, S=2048, D=1024, H=16, DH=64. Causal self-attention block, bf16 MFMA pipeline.

typedef __attribute__((ext_vector_type(8))) short bf16x8;   // 8 bf16 = 16B (A/B frag)
typedef __attribute__((ext_vector_type(4))) float f32x4;    // C/D frag 16x16
typedef __attribute__((ext_vector_type(16))) float f32x16;  // C/D frag 32x32
typedef __attribute__((ext_vector_type(4))) unsigned int u32x4;

typedef const __attribute__((address_space(1))) uint32_t* gp1_t;
typedef __attribute__((address_space(3))) uint32_t* lp3_t;

static __device__ __forceinline__ uint16_t f2b(float x) {
  __hip_bfloat16 h = __float2bfloat16(x);
  return *reinterpret_cast<uint16_t*>(&h);
}

// v_cvt_pk_bf16_f32: dst.lo = bf16(lo), dst.hi = bf16(hi)
static __device__ __forceinline__ uint32_t cvtpk(float lo, float hi) {
  uint32_t r;
  asm("v_cvt_pk_bf16_f32 %0, %1, %2" : "=v"(r) : "v"(lo), "v"(hi));
  return r;
}

// Stage R rows x 64 bf16 (128B = 8 chunks of 16B) tile into LDS (GEMMs only).
template <int ISSUES>
static __device__ __forceinline__ void stage64(const uint16_t* __restrict__ g, int gstride,
                                               uint8_t* lds, int t) {
#pragma unroll
  for (int i = 0; i < ISSUES; ++i) {
    int p = i * 256 + t;          // 16B-chunk index
    int row = p >> 3, c = p & 7;
    const uint16_t* src = g + row * gstride + ((c ^ (row & 7)) << 3);
    __builtin_amdgcn_global_load_lds((gp1_t)src, (lp3_t)(lds + (p & ~63) * 16), 16, 0, 0);
  }
}

// Read a 16B fragment from a swizzled [R][64] bf16 tile: 8 bf16 at (row, chunk*8).
static __device__ __forceinline__ bf16x8 ld_frag(const uint8_t* lds, int row, int chunk) {
  return *(const bf16x8*)(lds + row * 128 + (((chunk) ^ (row & 7)) << 4));
}

// ---------------- f32 -> bf16 convert ----------------
__global__ __launch_bounds__(256) void cvtk(const float* __restrict__ in,
                                            uint16_t* __restrict__ out, int n4) {
  int i = blockIdx.x * 256 + threadIdx.x;
  if (i >= n4) return;
  float4 v = ((const float4*)in)[i];
  ushort4 o;
  o.x = f2b(v.x); o.y = f2b(v.y); o.z = f2b(v.z); o.w = f2b(v.w);
  ((ushort4*)out)[i] = o;
}

// ---------------- GEMM1: qkv = x @ w_in^T + b_in ----------------
// Epilogue: Q pre-scaled by 1/sqrt(DH)*log2(e) (softmax done in exp2 domain).
// V stored transposed (B,H,DH,S) with column bits 2<->3 swapped inside each
// 16-col block, so attention's PV B-fragments are contiguous 16B loads while
// P stays fully lane-local (kv(ks,hi,j) = 32(ks>>1)+16(ks&1)+8(j>>2)+4hi+(j&3)).
__global__ __launch_bounds__(256) void gemm_qkv(const uint16_t* __restrict__ A,
                                                const uint16_t* __restrict__ W,
                                                const float* __restrict__ bias,
                                                uint16_t* __restrict__ Qb,
                                                uint16_t* __restrict__ Kb,
                                                uint16_t* __restrict__ Vt) {
  __shared__ uint8_t sm[32768];
  uint8_t* As = sm;
  uint8_t* Bs = sm + 16384;
  int t = threadIdx.x, l = t & 63, w = t >> 6;
  int m0 = blockIdx.y * 128, n0 = blockIdx.x * 128;
  int wr = (w >> 1) * 64, wc = (w & 1) * 64;
  const f32x4 fz = {0.f, 0.f, 0.f, 0.f};
  f32x4 acc[4][4];
#pragma unroll
  for (int i = 0; i < 4; ++i)
#pragma unroll
    for (int j = 0; j < 4; ++j) acc[i][j] = fz;

  for (int kt = 0; kt < 16; ++kt) {
    __syncthreads();
    stage64<4>(A + m0 * 1024 + kt * 64, 1024, As, t);
    stage64<4>(W + n0 * 1024 + kt * 64, 1024, Bs, t);
    __syncthreads();
#pragma unroll
    for (int ks = 0; ks < 2; ++ks) {
      bf16x8 a[4], b[4];
#pragma unroll
      for (int i = 0; i < 4; ++i) {
        a[i] = ld_frag(As, wr + i * 16 + (l & 15), ks * 4 + (l >> 4));
        b[i] = ld_frag(Bs, wc + i * 16 + (l & 15), ks * 4 + (l >> 4));
      }
#pragma unroll
      for (int i = 0; i < 4; ++i)
#pragma unroll
        for (int j = 0; j < 4; ++j)
          acc[i][j] = __builtin_amdgcn_mfma_f32_16x16x32_bf16(a[i], b[j], acc[i][j], 0, 0, 0);
    }
  }
  const float CSQ = 0.18033688011112042f;  // 0.125 * log2(e)
#pragma unroll
  for (int j = 0; j < 4; ++j) {
    int e = n0 + wc + j * 16 + (l & 15);
    float bv = bias[e];
    int sec = e >> 10, ec = e & 1023, h = ec >> 6, dh = ec & 63;
#pragma unroll
    for (int i = 0; i < 4; ++i) {
      int mb = m0 + wr + i * 16 + ((l >> 4) << 2);
#pragma unroll
      for (int r = 0; r < 4; ++r) {
        int m = mb + r, bb = m >> 11, s = m & 2047;
        float v = acc[i][j][r] + bv;
        if (sec == 0) {
          Qb[(((bb * 16 + h) * 2048 + s) << 6) + dh] = f2b(v * CSQ);
        } else if (sec == 1) {
          Kb[(((bb * 16 + h) * 2048 + s) << 6) + dh] = f2b(v);
        } else {
          int sp = (s & ~12) | ((s & 4) << 1) | ((s & 8) >> 1);  // swap col bits 2,3
          Vt[(((bb * 16 + h) << 6) + dh) * 2048 + sp] = f2b(v);
        }
      }
    }
  }
}

// ---------------- GEMM2: out = att @ w_out^T + b_out (f32 out) ----------------
__global__ __launch_bounds__(256) void gemm_out(const uint16_t* __restrict__ A,
                                                const uint16_t* __restrict__ W,
                                                const float* __restrict__ bias,
                                                float* __restrict__ out) {
  __shared__ uint8_t sm[32768];
  uint8_t* As = sm;
  uint8_t* Bs = sm + 16384;
  int t = threadIdx.x, l = t & 63, w = t >> 6;
  int m0 = blockIdx.y * 128, n0 = blockIdx.x * 128;
  int wr = (w >> 1) * 64, wc = (w & 1) * 64;
  const f32x4 fz = {0.f, 0.f, 0.f, 0.f};
  f32x4 acc[4][4];
#pragma unroll
  for (int i = 0; i < 4; ++i)
#pragma unroll
    for (int j = 0; j < 4; ++j) acc[i][j] = fz;

  for (int kt = 0; kt < 16; ++kt) {
    __syncthreads();
    stage64<4>(A + m0 * 1024 + kt * 64, 1024, As, t);
    stage64<4>(W + n0 * 1024 + kt * 64, 1024, Bs, t);
    __syncthreads();
#pragma unroll
    for (int ks = 0; ks < 2; ++ks) {
      bf16x8 a[4], b[4];
#pragma unroll
      for (int i = 0; i < 4; ++i) {
        a[i] = ld_frag(As, wr + i * 16 + (l & 15), ks * 4 + (l >> 4));
        b[i] = ld_frag(Bs, wc + i * 16 + (l & 15), ks * 4 + (l >> 4));
      }
#pragma unroll
      for (int i = 0; i < 4; ++i)
#pragma unroll
        for (int j = 0; j < 4; ++j)
          acc[i][j] = __builtin_amdgcn_mfma_f32_16x16x32_bf16(a[i], b[j], acc[i][j], 0, 0, 0);
    }
  }
#pragma unroll
  for (int j = 0; j < 4; ++j) {
    int e = n0 + wc + j * 16 + (l & 15);
    float bv = bias[e];
#pragma unroll
    for (int i = 0; i < 4; ++i) {
      int mb = m0 + wr + i * 16 + ((l >> 4) << 2);
#pragma unroll
      for (int r = 0; r < 4; ++r) {
        int m = mb + r;
        out[m * 1024 + e] = acc[i][j][r] + bv;
      }
    }
  }
}

// ---------------- Flash attention (causal): paired q-tiles, kv-split x2 ----------------
// Grid (32 pairs, 32 bh), 256 threads = 4 waves. Block p handles q-tiles
// qt = 63-p (heavy, waves 0-1) and qt = p (light, waves 2-3):
// nt(63-p) + nt(p) = 33..34 for ALL p -> every block has equal work, and the
// 1024 blocks = exactly 4 blocks/CU, all co-resident, no dispatch tail.
// Within a group the 2 waves kv-split (stride 2) with private (m,l,acco);
// pairwise merge via padded LDS at the end.
static __device__ __forceinline__ void load_kv(const uint16_t* __restrict__ kp,
                                               const uint16_t* __restrict__ vp,
                                               bf16x8 kf[2][4], bf16x8 vf[2][4]) {
#pragma unroll
  for (int f = 0; f < 2; ++f)
#pragma unroll
    for (int ks = 0; ks < 4; ++ks)
      kf[f][ks] = *(const bf16x8*)(kp + (f << 11) + ks * 16);
#pragma unroll
  for (int n = 0; n < 2; ++n)
#pragma unroll
    for (int ks = 0; ks < 4; ++ks)
      vf[n][ks] = *(const bf16x8*)(vp + n * 65536 + ks * 16);
}

static __device__ __forceinline__ void attn_tile(const bf16x8 kf[2][4], const bf16x8 vf[2][4],
                                                 const bf16x8 qf[4], f32x16 acco[2],
                                                 float& mrun, float& lsum,
                                                 int tt, int q0, int q, int hi, bool causal) {
  // QK^T: sc[f][r] = S[kv = tt*64 + f*32 + crow(r,hi)][q]  (already exp2-scaled)
  f32x16 sc[2];
#pragma unroll
  for (int r = 0; r < 16; ++r) { sc[0][r] = 0.f; sc[1][r] = 0.f; }
  __builtin_amdgcn_s_setprio(1);
#pragma unroll
  for (int f = 0; f < 2; ++f)
#pragma unroll
    for (int ks = 0; ks < 4; ++ks)
      sc[f] = __builtin_amdgcn_mfma_f32_32x32x16_bf16(kf[f][ks], qf[ks], sc[f], 0, 0, 0);
  __builtin_amdgcn_s_setprio(0);

  // causal mask + running max (in place on sc)
  float tm = -1e30f;
  bool nomask = (!causal) || (tt * 64 + 63 <= q0);
#pragma unroll
  for (int f = 0; f < 2; ++f)
#pragma unroll
    for (int r = 0; r < 16; ++r) {
      float v = sc[f][r];
      if (!nomask) {
        int kv = tt * 64 + f * 32 + ((r & 3) + 8 * (r >> 2) + 4 * hi);
        v = (kv <= q) ? v : -1e30f;
      }
      sc[f][r] = v;
      tm = fmaxf(tm, v);
    }
  tm = fmaxf(tm, __shfl_xor(tm, 32));

  // defer-max (T13): skip rescale when max growth small
  bool defer = __all(tm <= mrun + 8.0f);
  if (!defer) {
    float mnew = fmaxf(mrun, tm);
    float alpha = exp2f(mrun - mnew);
    mrun = mnew;
    lsum *= alpha;
#pragma unroll
    for (int r = 0; r < 16; ++r) {
      float av = __shfl(alpha, (r & 3) + 8 * (r >> 2) + 4 * hi);
      acco[0][r] *= av;
      acco[1][r] *= av;
    }
  }
  float rs = 0.f;
#pragma unroll
  for (int f = 0; f < 2; ++f)
#pragma unroll
    for (int r = 0; r < 16; ++r) {
      float e = exp2f(sc[f][r] - mrun);
      sc[f][r] = e;
      rs += e;
    }
  rs += __shfl_xor(rs, 32);
  lsum += rs;

  // PV with lane-local P fragments (zero cross-lane):
  __builtin_amdgcn_s_setprio(1);
#pragma unroll
  for (int ks = 0; ks < 4; ++ks) {
    int f = ks >> 1, a8 = (ks & 1) * 8;
    u32x4 wv = {cvtpk(sc[f][a8 + 0], sc[f][a8 + 1]),
                cvtpk(sc[f][a8 + 2], sc[f][a8 + 3]),
                cvtpk(sc[f][a8 + 4], sc[f][a8 + 5]),
                cvtpk(sc[f][a8 + 6], sc[f][a8 + 7])};
    bf16x8 af = __builtin_bit_cast(bf16x8, wv);
#pragma unroll
    for (int n = 0; n < 2; ++n)
      acco[n] = __builtin_amdgcn_mfma_f32_32x32x16_bf16(af, vf[n][ks], acco[n], 0, 0, 0);
  }
  __builtin_amdgcn_s_setprio(0);
}

__global__ __launch_bounds__(256) void attn(const uint16_t* __restrict__ Qb,
                                            const uint16_t* __restrict__ Kb,
                                            const uint16_t* __restrict__ Vt,
                                            uint16_t* __restrict__ Ab,
                                            const int* __restrict__ maskp) {
  __shared__ float oaccS[4][64][33];  // [wave][lane][reg], +1 pad -> conflict-free
  __shared__ float mlS[4][32][2];     // [wave][qrow][m,l]
  int t = threadIdx.x, l = t & 63, w = t >> 6;
  int hi = l >> 5, ql = l & 31;
  int p = blockIdx.x;               // pair index 0..31
  int g = w >> 1;                   // 0 = heavy (qt=63-p), 1 = light (qt=p)
  int ws = w & 1;                   // kv-split index within group
  int qt = g ? p : 63 - p;
  int bh = blockIdx.y;
  bool causal = (*maskp != 0);
  int nt = causal ? ((qt >> 1) + 1) : 32;
  int q0 = qt * 32;
  int q = q0 + ql;

  // Q fragments (B-operand): Q[q][dh = ks*16 + hi*8 + j], pre-scaled by CSQ
  bf16x8 qf[4];
  const uint16_t* Qp = Qb + (((size_t)bh * 2048 + q) << 6) + hi * 8;
#pragma unroll
  for (int ks = 0; ks < 4; ++ks) qf[ks] = *(const bf16x8*)(Qp + ks * 16);

  const uint16_t* Kp = Kb + (((size_t)bh * 2048) << 6) + (ql << 6) + hi * 8;
  const uint16_t* Vp = Vt + (size_t)bh * 131072 + (size_t)ql * 2048 + hi * 8;

  f32x16 acco[2];
#pragma unroll
  for (int r = 0; r < 16; ++r) { acco[0][r] = 0.f; acco[1][r] = 0.f; }
  float mrun = -1e30f, lsum = 0.f;

  // wave handles tiles ws, ws+2, ws+4, ... of its q-tile
  for (int tt = ws; tt < nt; tt += 2) {
    bf16x8 kf[2][4], vf[2][4];
    load_kv(Kp + ((size_t)tt << 12), Vp + tt * 64, kf, vf);
    attn_tile(kf, vf, qf, acco, mrun, lsum, tt, q0, q, hi, causal);
  }

  // ---- merge the 2 kv-split partials within each group ----
  if (hi == 0) { mlS[w][ql][0] = mrun; mlS[w][ql][1] = lsum; }
#pragma unroll
  for (int r = 0; r < 16; ++r) {
    oaccS[w][l][r] = acco[0][r];
    oaccS[w][l][16 + r] = acco[1][r];
  }
  __syncthreads();

  // group g uses slots {2g, 2g+1}; wave ws merges regs r = 8*ws + rr (rr 0..7)
  int s0 = 2 * g, s1 = 2 * g + 1;
  int bb = bh >> 4, h = bh & 15;
#pragma unroll
  for (int rr = 0; rr < 8; ++rr) {
    int r = 8 * ws + rr;
    int row = (r & 3) + 8 * (r >> 2) + 4 * hi;
    float m0v = mlS[s0][row][0], m1v = mlS[s1][row][0];
    float M = fmaxf(m0v, m1v);
    float w0 = exp2f(m0v - M), w1 = exp2f(m1v - M);
    float L = w0 * mlS[s0][row][1] + w1 * mlS[s1][row][1];
    float inv = 1.0f / L;
    int qg = q0 + row;
#pragma unroll
    for (int n = 0; n < 2; ++n) {
      float s = w0 * oaccS[s0][l][n * 16 + r] + w1 * oaccS[s1][l][n * 16 + r];
      Ab[(((size_t)(bb * 2048 + qg)) << 10) + h * 64 + n * 32 + ql] = f2b(s * inv);
    }
  }
}

extern "C" void kernel_launch(void* const* d_in, const int* in_sizes, int n_in,
                              void* d_out, int out_size, void* d_ws, size_t ws_size,
                              hipStream_t stream) {
  const float* x     = (const float*)d_in[0];
  const float* w_in  = (const float*)d_in[1];
  const float* b_in  = (const float*)d_in[2];
  const float* w_out = (const float*)d_in[3];
  const float* b_out = (const float*)d_in[4];
  const int*   mask  = (const int*)d_in[5];
  float* out = (float*)d_out;

  uint8_t* ws = (uint8_t*)d_ws;
  uint16_t* xb  = (uint16_t*)(ws);                  // 8 MB  x bf16 [4096][1024]
  uint16_t* wib = (uint16_t*)(ws + (8u << 20));     // 6 MB  w_in bf16 [3072][1024]
  uint16_t* wob = (uint16_t*)(ws + (14u << 20));    // 2 MB  w_out bf16 [1024][1024]
  uint16_t* Qb  = (uint16_t*)(ws + (16u << 20));    // 8 MB  (B,H,S,DH) pre-scaled
  uint16_t* Kb  = (uint16_t*)(ws + (24u << 20));    // 8 MB  (B,H,S,DH)
  uint16_t* Vt  = (uint16_t*)(ws + (32u << 20));    // 8 MB  (B,H,DH,S) col-permuted
  uint16_t* Ab  = (uint16_t*)(ws + (40u << 20));    // 8 MB  att (B,S,D) bf16

  cvtk<<<4096, 256, 0, stream>>>(x, xb, 4096 * 1024 / 4);
  cvtk<<<3072, 256, 0, stream>>>(w_in, wib, 3072 * 1024 / 4);
  cvtk<<<1024, 256, 0, stream>>>(w_out, wob, 1024 * 1024 / 4);
  gemm_qkv<<<dim3(24, 32), 256, 0, stream>>>(xb, wib, b_in, Qb, Kb, Vt);
  attn<<<dim3(32, 32), 256, 0, stream>>>(Qb, Kb, Vt, Ab, mask);
  gemm_out<<<dim3(8, 32), 256, 0, stream>>>(Ab, wob, b_out, out);
}

// Round 8
// 172.813 us; speedup vs baseline: 1.2354x; 1.0076x over previous
//
#include <hip/hip_runtime.h>
#include <hip/hip_bf16.h>
#include <stdint.h>

// B=2, S=2048, D=1024, H=16, DH=64. Causal self-attention block, bf16 MFMA pipeline.

typedef __attribute__((ext_vector_type(8))) short bf16x8;   // 8 bf16 = 16B (A/B frag)
typedef __attribute__((ext_vector_type(4))) float f32x4;    // C/D frag 16x16
typedef __attribute__((ext_vector_type(16))) float f32x16;  // C/D frag 32x32
typedef __attribute__((ext_vector_type(4))) unsigned int u32x4;

typedef const __attribute__((address_space(1))) uint32_t* gp1_t;
typedef __attribute__((address_space(3))) uint32_t* lp3_t;

static __device__ __forceinline__ uint16_t f2b(float x) {
  __hip_bfloat16 h = __float2bfloat16(x);
  return *reinterpret_cast<uint16_t*>(&h);
}

// v_cvt_pk_bf16_f32: dst.lo = bf16(lo), dst.hi = bf16(hi)
static __device__ __forceinline__ uint32_t cvtpk(float lo, float hi) {
  uint32_t r;
  asm("v_cvt_pk_bf16_f32 %0, %1, %2" : "=v"(r) : "v"(lo), "v"(hi));
  return r;
}

// Stage R rows x 64 bf16 (128B = 8 chunks of 16B) tile into LDS (GEMMs only).
template <int ISSUES>
static __device__ __forceinline__ void stage64(const uint16_t* __restrict__ g, int gstride,
                                               uint8_t* lds, int t) {
#pragma unroll
  for (int i = 0; i < ISSUES; ++i) {
    int p = i * 256 + t;          // 16B-chunk index
    int row = p >> 3, c = p & 7;
    const uint16_t* src = g + row * gstride + ((c ^ (row & 7)) << 3);
    __builtin_amdgcn_global_load_lds((gp1_t)src, (lp3_t)(lds + (p & ~63) * 16), 16, 0, 0);
  }
}

// Read a 16B fragment from a swizzled [R][64] bf16 tile: 8 bf16 at (row, chunk*8).
static __device__ __forceinline__ bf16x8 ld_frag(const uint8_t* lds, int row, int chunk) {
  return *(const bf16x8*)(lds + row * 128 + (((chunk) ^ (row & 7)) << 4));
}

// ---------------- f32 -> bf16 convert ----------------
__global__ __launch_bounds__(256) void cvtk(const float* __restrict__ in,
                                            uint16_t* __restrict__ out, int n4) {
  int i = blockIdx.x * 256 + threadIdx.x;
  if (i >= n4) return;
  float4 v = ((const float4*)in)[i];
  ushort4 o;
  o.x = f2b(v.x); o.y = f2b(v.y); o.z = f2b(v.z); o.w = f2b(v.w);
  ((ushort4*)out)[i] = o;
}

// ---------------- GEMM1: qkv = x @ w_in^T + b_in ----------------
// Epilogue: Q pre-scaled by 1/sqrt(DH)*log2(e) (softmax done in exp2 domain).
// V stored transposed (B,H,DH,S) with column bits 2<->3 swapped inside each
// 16-col block, so attention's PV B-fragments are contiguous 16B loads while
// P stays fully lane-local (kv(ks,hi,j) = 32(ks>>1)+16(ks&1)+8(j>>2)+4hi+(j&3)).
__global__ __launch_bounds__(256) void gemm_qkv(const uint16_t* __restrict__ A,
                                                const uint16_t* __restrict__ W,
                                                const float* __restrict__ bias,
                                                uint16_t* __restrict__ Qb,
                                                uint16_t* __restrict__ Kb,
                                                uint16_t* __restrict__ Vt) {
  __shared__ uint8_t sm[32768];
  uint8_t* As = sm;
  uint8_t* Bs = sm + 16384;
  int t = threadIdx.x, l = t & 63, w = t >> 6;
  int m0 = blockIdx.y * 128, n0 = blockIdx.x * 128;
  int wr = (w >> 1) * 64, wc = (w & 1) * 64;
  const f32x4 fz = {0.f, 0.f, 0.f, 0.f};
  f32x4 acc[4][4];
#pragma unroll
  for (int i = 0; i < 4; ++i)
#pragma unroll
    for (int j = 0; j < 4; ++j) acc[i][j] = fz;

  for (int kt = 0; kt < 16; ++kt) {
    __syncthreads();
    stage64<4>(A + m0 * 1024 + kt * 64, 1024, As, t);
    stage64<4>(W + n0 * 1024 + kt * 64, 1024, Bs, t);
    __syncthreads();
#pragma unroll
    for (int ks = 0; ks < 2; ++ks) {
      bf16x8 a[4], b[4];
#pragma unroll
      for (int i = 0; i < 4; ++i) {
        a[i] = ld_frag(As, wr + i * 16 + (l & 15), ks * 4 + (l >> 4));
        b[i] = ld_frag(Bs, wc + i * 16 + (l & 15), ks * 4 + (l >> 4));
      }
#pragma unroll
      for (int i = 0; i < 4; ++i)
#pragma unroll
        for (int j = 0; j < 4; ++j)
          acc[i][j] = __builtin_amdgcn_mfma_f32_16x16x32_bf16(a[i], b[j], acc[i][j], 0, 0, 0);
    }
  }
  const float CSQ = 0.18033688011112042f;  // 0.125 * log2(e)
#pragma unroll
  for (int j = 0; j < 4; ++j) {
    int e = n0 + wc + j * 16 + (l & 15);
    float bv = bias[e];
    int sec = e >> 10, ec = e & 1023, h = ec >> 6, dh = ec & 63;
#pragma unroll
    for (int i = 0; i < 4; ++i) {
      int mb = m0 + wr + i * 16 + ((l >> 4) << 2);
#pragma unroll
      for (int r = 0; r < 4; ++r) {
        int m = mb + r, bb = m >> 11, s = m & 2047;
        float v = acc[i][j][r] + bv;
        if (sec == 0) {
          Qb[(((bb * 16 + h) * 2048 + s) << 6) + dh] = f2b(v * CSQ);
        } else if (sec == 1) {
          Kb[(((bb * 16 + h) * 2048 + s) << 6) + dh] = f2b(v);
        } else {
          int sp = (s & ~12) | ((s & 4) << 1) | ((s & 8) >> 1);  // swap col bits 2,3
          Vt[(((bb * 16 + h) << 6) + dh) * 2048 + sp] = f2b(v);
        }
      }
    }
  }
}

// ---------------- GEMM2: out = att @ w_out^T + b_out (f32 out) ----------------
__global__ __launch_bounds__(256) void gemm_out(const uint16_t* __restrict__ A,
                                                const uint16_t* __restrict__ W,
                                                const float* __restrict__ bias,
                                                float* __restrict__ out) {
  __shared__ uint8_t sm[32768];
  uint8_t* As = sm;
  uint8_t* Bs = sm + 16384;
  int t = threadIdx.x, l = t & 63, w = t >> 6;
  int m0 = blockIdx.y * 128, n0 = blockIdx.x * 128;
  int wr = (w >> 1) * 64, wc = (w & 1) * 64;
  const f32x4 fz = {0.f, 0.f, 0.f, 0.f};
  f32x4 acc[4][4];
#pragma unroll
  for (int i = 0; i < 4; ++i)
#pragma unroll
    for (int j = 0; j < 4; ++j) acc[i][j] = fz;

  for (int kt = 0; kt < 16; ++kt) {
    __syncthreads();
    stage64<4>(A + m0 * 1024 + kt * 64, 1024, As, t);
    stage64<4>(W + n0 * 1024 + kt * 64, 1024, Bs, t);
    __syncthreads();
#pragma unroll
    for (int ks = 0; ks < 2; ++ks) {
      bf16x8 a[4], b[4];
#pragma unroll
      for (int i = 0; i < 4; ++i) {
        a[i] = ld_frag(As, wr + i * 16 + (l & 15), ks * 4 + (l >> 4));
        b[i] = ld_frag(Bs, wc + i * 16 + (l & 15), ks * 4 + (l >> 4));
      }
#pragma unroll
      for (int i = 0; i < 4; ++i)
#pragma unroll
        for (int j = 0; j < 4; ++j)
          acc[i][j] = __builtin_amdgcn_mfma_f32_16x16x32_bf16(a[i], b[j], acc[i][j], 0, 0, 0);
    }
  }
#pragma unroll
  for (int j = 0; j < 4; ++j) {
    int e = n0 + wc + j * 16 + (l & 15);
    float bv = bias[e];
#pragma unroll
    for (int i = 0; i < 4; ++i) {
      int mb = m0 + wr + i * 16 + ((l >> 4) << 2);
#pragma unroll
      for (int r = 0; r < 4; ++r) {
        int m = mb + r;
        out[m * 1024 + e] = acc[i][j][r] + bv;
      }
    }
  }
}

// ---------------- Flash attention (causal): 2 balanced phases, kv-split x4 ----------------
// Grid (32, 32), 256 threads = 4 waves. Block p runs TWO sequential phases, each
// with all 4 waves kv-splitting one q-tile (stride 4): phase 0 -> qt=63-p (heavy),
// phase 1 -> qt=p (light). Per-wave tiles = ceil(nt_h/4)+ceil(nt_l/4) = 8..9 for
// every wave of every block (nt_h+nt_l = 33..34) -> 1024 equal blocks, 4/CU, all
// waves active ~whole kernel. 4-way merge via padded LDS after each phase.
// NF=1 tiles skip the fully-masked upper 32 kv rows (diagonal tile of even qt).
template <int NF>
static __device__ __forceinline__ void load_kv(const uint16_t* __restrict__ kp,
                                               const uint16_t* __restrict__ vp,
                                               bf16x8 kf[2][4], bf16x8 vf[2][4]) {
#pragma unroll
  for (int f = 0; f < NF; ++f)
#pragma unroll
    for (int ks = 0; ks < 4; ++ks)
      kf[f][ks] = *(const bf16x8*)(kp + (f << 11) + ks * 16);
#pragma unroll
  for (int n = 0; n < 2; ++n)
#pragma unroll
    for (int ks = 0; ks < 2 * NF; ++ks)
      vf[n][ks] = *(const bf16x8*)(vp + n * 65536 + ks * 16);
}

template <int NF>
static __device__ __forceinline__ void attn_tile(const bf16x8 kf[2][4], const bf16x8 vf[2][4],
                                                 const bf16x8 qf[4], f32x16 acco[2],
                                                 float& mrun, float& lsum,
                                                 int tt, int q0, int q, int hi, bool causal) {
  // QK^T: sc[f][r] = S[kv = tt*64 + f*32 + crow(r,hi)][q]  (already exp2-scaled)
  f32x16 sc[2];
#pragma unroll
  for (int f = 0; f < NF; ++f)
#pragma unroll
    for (int r = 0; r < 16; ++r) sc[f][r] = 0.f;
  __builtin_amdgcn_s_setprio(1);
#pragma unroll
  for (int f = 0; f < NF; ++f)
#pragma unroll
    for (int ks = 0; ks < 4; ++ks)
      sc[f] = __builtin_amdgcn_mfma_f32_32x32x16_bf16(kf[f][ks], qf[ks], sc[f], 0, 0, 0);
  __builtin_amdgcn_s_setprio(0);

  // causal mask + running max (in place on sc)
  float tm = -1e30f;
  bool nomask = (!causal) || (tt * 64 + 63 <= q0);
#pragma unroll
  for (int f = 0; f < NF; ++f)
#pragma unroll
    for (int r = 0; r < 16; ++r) {
      float v = sc[f][r];
      if (!nomask) {
        int kv = tt * 64 + f * 32 + ((r & 3) + 8 * (r >> 2) + 4 * hi);
        v = (kv <= q) ? v : -1e30f;
      }
      sc[f][r] = v;
      tm = fmaxf(tm, v);
    }
  tm = fmaxf(tm, __shfl_xor(tm, 32));

  // defer-max (T13): skip rescale when max growth small
  bool defer = __all(tm <= mrun + 8.0f);
  if (!defer) {
    float mnew = fmaxf(mrun, tm);
    float alpha = exp2f(mrun - mnew);
    mrun = mnew;
    lsum *= alpha;
#pragma unroll
    for (int r = 0; r < 16; ++r) {
      float av = __shfl(alpha, (r & 3) + 8 * (r >> 2) + 4 * hi);
      acco[0][r] *= av;
      acco[1][r] *= av;
    }
  }
  float rs = 0.f;
#pragma unroll
  for (int f = 0; f < NF; ++f)
#pragma unroll
    for (int r = 0; r < 16; ++r) {
      float e = exp2f(sc[f][r] - mrun);
      sc[f][r] = e;
      rs += e;
    }
  rs += __shfl_xor(rs, 32);
  lsum += rs;

  // PV with lane-local P fragments (zero cross-lane):
  __builtin_amdgcn_s_setprio(1);
#pragma unroll
  for (int ks = 0; ks < 2 * NF; ++ks) {
    int f = ks >> 1, a8 = (ks & 1) * 8;
    u32x4 wv = {cvtpk(sc[f][a8 + 0], sc[f][a8 + 1]),
                cvtpk(sc[f][a8 + 2], sc[f][a8 + 3]),
                cvtpk(sc[f][a8 + 4], sc[f][a8 + 5]),
                cvtpk(sc[f][a8 + 6], sc[f][a8 + 7])};
    bf16x8 af = __builtin_bit_cast(bf16x8, wv);
#pragma unroll
    for (int n = 0; n < 2; ++n)
      acco[n] = __builtin_amdgcn_mfma_f32_32x32x16_bf16(af, vf[n][ks], acco[n], 0, 0, 0);
  }
  __builtin_amdgcn_s_setprio(0);
}

__global__ __launch_bounds__(256) void attn(const uint16_t* __restrict__ Qb,
                                            const uint16_t* __restrict__ Kb,
                                            const uint16_t* __restrict__ Vt,
                                            uint16_t* __restrict__ Ab,
                                            const int* __restrict__ maskp) {
  __shared__ float oaccS[4][64][33];  // [wave][lane][reg], +1 pad -> conflict-free
  __shared__ float mlS[4][32][2];     // [wave][qrow][m,l]
  int t = threadIdx.x, l = t & 63, w = t >> 6;
  int hi = l >> 5, ql = l & 31;
  int p = blockIdx.x;               // pair index 0..31
  int bh = blockIdx.y;
  bool causal = (*maskp != 0);
  int bb = bh >> 4, h = bh & 15;

  const uint16_t* Kp = Kb + (((size_t)bh * 2048) << 6) + (ql << 6) + hi * 8;
  const uint16_t* Vp = Vt + (size_t)bh * 131072 + (size_t)ql * 2048 + hi * 8;

  for (int ph = 0; ph < 2; ++ph) {
    int qt = ph ? p : 63 - p;
    int nt = causal ? ((qt >> 1) + 1) : 32;
    int q0 = qt * 32;
    int q = q0 + ql;

    // Q fragments (B-operand): Q[q][dh = ks*16 + hi*8 + j], pre-scaled by CSQ
    bf16x8 qf[4];
    const uint16_t* Qp = Qb + (((size_t)bh * 2048 + q) << 6) + hi * 8;
#pragma unroll
    for (int ks = 0; ks < 4; ++ks) qf[ks] = *(const bf16x8*)(Qp + ks * 16);

    f32x16 acco[2];
#pragma unroll
    for (int r = 0; r < 16; ++r) { acco[0][r] = 0.f; acco[1][r] = 0.f; }
    float mrun = -1e30f, lsum = 0.f;

    // wave w handles tiles w, w+4, ... of this q-tile
    for (int tt = w; tt < nt; tt += 4) {
      bf16x8 kf[2][4], vf[2][4];
      bool full = !(causal && 2 * tt >= qt);  // upper 32 kv rows fully masked?
      if (full) {
        load_kv<2>(Kp + ((size_t)tt << 12), Vp + tt * 64, kf, vf);
        attn_tile<2>(kf, vf, qf, acco, mrun, lsum, tt, q0, q, hi, causal);
      } else {
        load_kv<1>(Kp + ((size_t)tt << 12), Vp + tt * 64, kf, vf);
        attn_tile<1>(kf, vf, qf, acco, mrun, lsum, tt, q0, q, hi, causal);
      }
    }

    // ---- 4-way kv-split merge via LDS ----
    if (hi == 0) { mlS[w][ql][0] = mrun; mlS[w][ql][1] = lsum; }
#pragma unroll
    for (int r = 0; r < 16; ++r) {
      oaccS[w][l][r] = acco[0][r];
      oaccS[w][l][16 + r] = acco[1][r];
    }
    __syncthreads();

    // wave w merges register subset r in [4w, 4w+4)  (rows 8w + 4hi + 0..3)
#pragma unroll
    for (int rr = 0; rr < 4; ++rr) {
      int row = 8 * w + 4 * hi + rr;
      int r = 4 * w + rr;
      float m0v = mlS[0][row][0], m1v = mlS[1][row][0];
      float m2v = mlS[2][row][0], m3v = mlS[3][row][0];
      float M = fmaxf(fmaxf(m0v, m1v), fmaxf(m2v, m3v));
      float w0 = exp2f(m0v - M), w1 = exp2f(m1v - M);
      float w2 = exp2f(m2v - M), w3 = exp2f(m3v - M);
      float L = w0 * mlS[0][row][1] + w1 * mlS[1][row][1] +
                w2 * mlS[2][row][1] + w3 * mlS[3][row][1];
      float inv = 1.0f / L;
      int qg = q0 + row;
#pragma unroll
      for (int n = 0; n < 2; ++n) {
        float s = w0 * oaccS[0][l][n * 16 + r] + w1 * oaccS[1][l][n * 16 + r] +
                  w2 * oaccS[2][l][n * 16 + r] + w3 * oaccS[3][l][n * 16 + r];
        Ab[(((size_t)(bb * 2048 + qg)) << 10) + h * 64 + n * 32 + ql] = f2b(s * inv);
      }
    }
    __syncthreads();  // LDS reuse fence before next phase's writes
  }
}

extern "C" void kernel_launch(void* const* d_in, const int* in_sizes, int n_in,
                              void* d_out, int out_size, void* d_ws, size_t ws_size,
                              hipStream_t stream) {
  const float* x     = (const float*)d_in[0];
  const float* w_in  = (const float*)d_in[1];
  const float* b_in  = (const float*)d_in[2];
  const float* w_out = (const float*)d_in[3];
  const float* b_out = (const float*)d_in[4];
  const int*   mask  = (const int*)d_in[5];
  float* out = (float*)d_out;

  uint8_t* ws = (uint8_t*)d_ws;
  uint16_t* xb  = (uint16_t*)(ws);                  // 8 MB  x bf16 [4096][1024]
  uint16_t* wib = (uint16_t*)(ws + (8u << 20));     // 6 MB  w_in bf16 [3072][1024]
  uint16_t* wob = (uint16_t*)(ws + (14u << 20));    // 2 MB  w_out bf16 [1024][1024]
  uint16_t* Qb  = (uint16_t*)(ws + (16u << 20));    // 8 MB  (B,H,S,DH) pre-scaled
  uint16_t* Kb  = (uint16_t*)(ws + (24u << 20));    // 8 MB  (B,H,S,DH)
  uint16_t* Vt  = (uint16_t*)(ws + (32u << 20));    // 8 MB  (B,H,DH,S) col-permuted
  uint16_t* Ab  = (uint16_t*)(ws + (40u << 20));    // 8 MB  att (B,S,D) bf16

  cvtk<<<4096, 256, 0, stream>>>(x, xb, 4096 * 1024 / 4);
  cvtk<<<3072, 256, 0, stream>>>(w_in, wib, 3072 * 1024 / 4);
  cvtk<<<1024, 256, 0, stream>>>(w_out, wob, 1024 * 1024 / 4);
  gemm_qkv<<<dim3(24, 32), 256, 0, stream>>>(xb, wib, b_in, Qb, Kb, Vt);
  attn<<<dim3(32, 32), 256, 0, stream>>>(Qb, Kb, Vt, Ab, mask);
  gemm_out<<<dim3(8, 32), 256, 0, stream>>>(Ab, wob, b_out, out);
}